// Round 14
// baseline (832.547 us; speedup 1.0000x reference)
//
#include <hip/hip_runtime.h>
#include <stdint.h>
#include <math.h>
#include <limits.h>

#define EPS 1e-5f

typedef __attribute__((ext_vector_type(4))) __bf16 bf16x4;
typedef __attribute__((ext_vector_type(8))) __bf16 bf16x8;
typedef __attribute__((ext_vector_type(16))) float f32x16;
typedef float f32x4u __attribute__((ext_vector_type(4), aligned(4)));

// ---------------------------------------------------------------------------
// prep_all v2: merged one-shot prep. FC weight packing one-thread-per-word.
// blocks: [0,198) wprep | [198,273) pw2 | [273,381) pw3 | [381,543) pw4 |
//         [543,651) pw5 | [651,5259) pwf1 | [5259,7307) pwf2
// ---------------------------------------------------------------------------
__device__ __forceinline__ void packw_body(
    const float* __restrict__ w, uint32_t* __restrict__ out,
    int C, int KK, int total, int idx)
{
    if (idx >= total) return;
    int kk = idx % KK, t = idx / KK;
    int cw = t % (C / 32); int o = t / (C / 32);
    const float* base = w + ((size_t)o * C + cw * 32) * KK + kk;
    uint32_t word = 0;
    #pragma unroll
    for (int j = 0; j < 32; ++j)
        word |= (base[(size_t)j * KK] < 0.f) ? (1u << j) : 0u;
    out[idx] = word;
}

__device__ __forceinline__ void packword_body(
    const float* __restrict__ in, uint32_t* __restrict__ out, int idx)
{
    const float* base = in + (size_t)idx * 32;   // 128B-aligned
    uint32_t word = 0;
    #pragma unroll
    for (int q = 0; q < 8; ++q) {
        float4 v = *(const float4*)(base + q * 4);
        word |= (v.x < 0.f) ? (1u << (q * 4 + 0)) : 0u;
        word |= (v.y < 0.f) ? (1u << (q * 4 + 1)) : 0u;
        word |= (v.z < 0.f) ? (1u << (q * 4 + 2)) : 0u;
        word |= (v.w < 0.f) ? (1u << (q * 4 + 3)) : 0u;
    }
    out[idx] = word;
}

__global__ __launch_bounds__(256) void prep_all(
    const float* __restrict__ conv1_w, __bf16* __restrict__ wth, __bf16* __restrict__ wtl,
    const float* __restrict__ w2, uint32_t* __restrict__ pw2,
    const float* __restrict__ w3, uint32_t* __restrict__ pw3,
    const float* __restrict__ w4, uint32_t* __restrict__ pw4,
    const float* __restrict__ w5, uint32_t* __restrict__ pw5,
    const float* __restrict__ blin1, uint32_t* __restrict__ pwf1,
    const float* __restrict__ blin2, uint32_t* __restrict__ pwf2)
{
    const int blk = blockIdx.x;
    const int tid = threadIdx.x;
    if (blk < 198) {
        int idx = blk * 256 + tid;   // 96*33*16 = 50688 exact
        if (idx >= 96 * 33 * 16) return;
        int kw = idx & 15;
        int kr = (idx >> 4) % 33;
        int og = idx / (16 * 33);
        int ot = og >> 5, o = og & 31;
        float v = 0.f;
        if (kw < 11) v = conv1_w[og * 363 + kr * 11 + kw];
        __bf16 h = (__bf16)v;
        size_t dst = ((size_t)(ot * 33 + kr) * 32 + o) * 16 + kw;
        wth[dst] = h;
        wtl[dst] = (__bf16)(v - (float)h);
    } else if (blk < 273) {
        packw_body(w2, pw2, 96, 25, 256 * 3 * 25, (blk - 198) * 256 + tid);
    } else if (blk < 381) {
        packw_body(w3, pw3, 256, 9, 384 * 8 * 9, (blk - 273) * 256 + tid);
    } else if (blk < 543) {
        packw_body(w4, pw4, 384, 9, 384 * 12 * 9, (blk - 381) * 256 + tid);
    } else if (blk < 651) {
        packw_body(w5, pw5, 384, 9, 256 * 12 * 9, (blk - 543) * 256 + tid);
    } else if (blk < 5259) {
        packword_body(blin1, pwf1, (blk - 651) * 256 + tid);   // 1,179,648 exact
    } else {
        packword_body(blin2, pwf2, (blk - 5259) * 256 + tid);  //   524,288 exact
    }
}

// ---------------------------------------------------------------------------
// conv1 via MFMA v6: v3 compute, but LDS holds ONE input channel's 23 rows
// at a time (24.3 KB vs 73 KB) with a barrier per phase -> 4 blocks/CU
// (wave cap) = 32 waves/CU, double v3's occupancy. Numerics identical.
// block = (oy-quad, b), 8 waves = (yh, xt); channel-last output.
// ---------------------------------------------------------------------------
__global__ __launch_bounds__(512) void conv1_mfma(
    const float* __restrict__ x, const __bf16* __restrict__ wth,
    const __bf16* __restrict__ wtl, float* __restrict__ out)
{
    const int byq = blockIdx.x;   // 0..13 -> oy = 4*byq + yh
    const int b   = blockIdx.y;
    __shared__ __bf16 ldsbuf[2 * 23 * 264 + 16];   // 24,320 B
    __bf16* ldsH = ldsbuf;
    __bf16* ldsL = ldsbuf + 23 * 264 + 8;

    const float* xb = x + (size_t)b * 3 * 224 * 224;
    const int iy0 = 16 * byq - 2;

    const int wv = threadIdx.x >> 6;
    const int l  = threadIdx.x & 63;
    const int yh = wv >> 1, xt = wv & 1;
    const int col = l & 31, kg = l >> 5;
    const int oy = 4 * byq + yh;

    f32x16 acc0 = {}, acc1 = {}, acc2 = {};
    const int bpos = 4 * (xt * 32 + col) + 8 * kg;
    const int wofs = col * 16 + kg * 8;

    for (int c = 0; c < 3; ++c) {
        // stage this channel's 23 padded rows
        for (int idx = threadIdx.x; idx < 23 * 33; idx += 512) {
            int r = idx / 33, q = idx % 33;
            int iy = iy0 + r;
            const float* src = xb + ((size_t)c * 224 + iy) * 224;
            int ix0 = q * 8 - 2;
            bf16x8 hv, lv;
            if ((unsigned)iy < 224u && ix0 >= 0 && ix0 + 7 <= 223) {
                f32x4u f0 = *(const f32x4u*)(src + ix0);
                f32x4u f1 = *(const f32x4u*)(src + ix0 + 4);
                #pragma unroll
                for (int j = 0; j < 4; ++j) {
                    __bf16 h0 = (__bf16)f0[j];
                    hv[j] = h0; lv[j] = (__bf16)(f0[j] - (float)h0);
                    __bf16 h1 = (__bf16)f1[j];
                    hv[4 + j] = h1; lv[4 + j] = (__bf16)(f1[j] - (float)h1);
                }
            } else {
                #pragma unroll
                for (int j = 0; j < 8; ++j) {
                    int ix = ix0 + j;
                    float v = 0.f;
                    if ((unsigned)iy < 224u && (unsigned)ix < 224u) v = src[ix];
                    __bf16 h = (__bf16)v;
                    hv[j] = h;
                    lv[j] = (__bf16)(v - (float)h);
                }
            }
            *(bf16x8*)(ldsH + r * 264 + q * 8) = hv;
            *(bf16x8*)(ldsL + r * 264 + q * 8) = lv;
        }
        __syncthreads();

        #pragma unroll
        for (int kh = 0; kh < 11; ++kh) {
            const int kr = c * 11 + kh;
            const int rowoff = (4 * yh + kh) * 264 + bpos;
            bf16x4 bh0 = *(const bf16x4*)(ldsH + rowoff);
            bf16x4 bh1 = *(const bf16x4*)(ldsH + rowoff + 4);
            bf16x4 bl0 = *(const bf16x4*)(ldsL + rowoff);
            bf16x4 bl1 = *(const bf16x4*)(ldsL + rowoff + 4);
            bf16x8 bh = __builtin_shufflevector(bh0, bh1, 0, 1, 2, 3, 4, 5, 6, 7);
            bf16x8 bl = __builtin_shufflevector(bl0, bl1, 0, 1, 2, 3, 4, 5, 6, 7);
            {
                bf16x8 ah = *(const bf16x8*)(wth + (size_t)kr * 512 + wofs);
                bf16x8 aL = *(const bf16x8*)(wtl + (size_t)kr * 512 + wofs);
                acc0 = __builtin_amdgcn_mfma_f32_32x32x16_bf16(bh, ah, acc0, 0, 0, 0);
                acc0 = __builtin_amdgcn_mfma_f32_32x32x16_bf16(bl, ah, acc0, 0, 0, 0);
                acc0 = __builtin_amdgcn_mfma_f32_32x32x16_bf16(bh, aL, acc0, 0, 0, 0);
            }
            {
                bf16x8 ah = *(const bf16x8*)(wth + (size_t)(33 + kr) * 512 + wofs);
                bf16x8 aL = *(const bf16x8*)(wtl + (size_t)(33 + kr) * 512 + wofs);
                acc1 = __builtin_amdgcn_mfma_f32_32x32x16_bf16(bh, ah, acc1, 0, 0, 0);
                acc1 = __builtin_amdgcn_mfma_f32_32x32x16_bf16(bl, ah, acc1, 0, 0, 0);
                acc1 = __builtin_amdgcn_mfma_f32_32x32x16_bf16(bh, aL, acc1, 0, 0, 0);
            }
            {
                bf16x8 ah = *(const bf16x8*)(wth + (size_t)(66 + kr) * 512 + wofs);
                bf16x8 aL = *(const bf16x8*)(wtl + (size_t)(66 + kr) * 512 + wofs);
                acc2 = __builtin_amdgcn_mfma_f32_32x32x16_bf16(bh, ah, acc2, 0, 0, 0);
                acc2 = __builtin_amdgcn_mfma_f32_32x32x16_bf16(bl, ah, acc2, 0, 0, 0);
                acc2 = __builtin_amdgcn_mfma_f32_32x32x16_bf16(bh, aL, acc2, 0, 0, 0);
            }
        }
        if (c < 2) __syncthreads();   // protect buffer before next stage
    }

    if (oy < 55) {
        #pragma unroll
        for (int i = 0; i < 16; ++i) {
            int oxr = (i & 3) + 8 * (i >> 2) + 4 * kg;
            int ox = xt * 32 + oxr;
            if (ox < 55) {
                float* p = out + ((size_t)(b * 55 + oy) * 55 + ox) * 96 + col;
                p[0]  = acc0[i];
                p[32] = acc1[i];
                p[64] = acc2[i];
            }
        }
    }
}

// ---------------------------------------------------------------------------
// stage1 v2: A [b][55][55][96] (channel-last) -> maxpool3x3s2 -> bn1 -> sign
// -> pack pad2 -> PB1 [128,3,31,31]. Vectorized float4 channel reads.
// ---------------------------------------------------------------------------
__global__ __launch_bounds__(256) void poolpack1(
    const float* __restrict__ A, uint32_t* __restrict__ pout,
    const float* __restrict__ bnp)
{
    int idx = blockIdx.x * 256 + threadIdx.x;
    if (idx >= 128 * 3 * 31 * 31) return;
    int xp = idx % 31, t = idx / 31;
    int yp = t % 31; t /= 31;
    int cw = t % 3; int b = t / 3;
    uint32_t word = 0xFFFFFFFFu;
    if (yp >= 2 && yp <= 28 && xp >= 2 && xp <= 28) {
        int py = yp - 2, px = xp - 2;
        const float* base = A + ((size_t)(b * 55 + 2 * py) * 55 + 2 * px) * 96 + cw * 32;
        word = 0u;
        #pragma unroll
        for (int q = 0; q < 8; ++q) {
            float4 mx = *(const float4*)(base + q * 4);
            #pragma unroll
            for (int dy = 0; dy < 3; ++dy)
                #pragma unroll
                for (int dx = 0; dx < 3; ++dx) {
                    if (dy == 0 && dx == 0) continue;
                    float4 v = *(const float4*)(base + (dy * 55 + dx) * 96 + q * 4);
                    mx.x = fmaxf(mx.x, v.x); mx.y = fmaxf(mx.y, v.y);
                    mx.z = fmaxf(mx.z, v.z); mx.w = fmaxf(mx.w, v.w);
                }
            float mm[4] = {mx.x, mx.y, mx.z, mx.w};
            #pragma unroll
            for (int j = 0; j < 4; ++j) {
                int c = cw * 32 + q * 4 + j;
                float scale = bnp[c] / sqrtf(bnp[288 + c] + EPS);
                float bnv = (mm[j] - bnp[192 + c]) * scale + bnp[96 + c];
                if (bnv < 0.f) word |= 1u << (q * 4 + j);
            }
        }
    }
    pout[idx] = word;
}

// ---------------------------------------------------------------------------
// binconv2 + maxpool + bn2 + sign + pack pad1, v3 STREAMING.
// grid (3, 2, 128), block 256 = (o_local 128, xhalf 2)
// ---------------------------------------------------------------------------
__global__ __launch_bounds__(256) void binconv2_pool(
    const uint32_t* __restrict__ pa, const uint32_t* __restrict__ pw,
    uint32_t* __restrict__ pout, const float* __restrict__ bnp)
{
    const int third = blockIdx.x, ot = blockIdx.y, b = blockIdx.z;
    __shared__ uint32_t wl[75 * 129];
    __shared__ alignas(16) uint32_t al[2976];

    const uint32_t* pwb = pw + (size_t)(ot * 128) * 75;
    for (int idx = threadIdx.x; idx < 128 * 75; idx += 256) {
        int o = idx / 75, k = idx % 75;
        wl[k * 129 + o] = pwb[idx];
    }
    const uint32_t* pab = pa + (size_t)b * 3 * 961;
    for (int idx = threadIdx.x; idx < 2976; idx += 256) {
        int cw = idx / 992, rem = idx - cw * 992;
        int row = rem >> 5, xp = rem & 31;
        al[idx] = (xp < 31) ? pab[(size_t)cw * 961 + row * 31 + xp] : 0u;
    }
    __syncthreads();

    const int ol = threadIdx.x & 127;
    const int xh = threadIdx.x >> 7;
    const int xs = xh * 12;
    const int o = ot * 128 + ol;
    const float scale = bnp[o] / sqrtf(bnp[768 + o] + EPS);
    const float bmean = bnp[512 + o], bbeta = bnp[256 + o];
    const int lane = threadIdx.x & 63;
    const int cwbase = ot * 4 + ((threadIdx.x >> 6) & 1) * 2;

    const int pyS = (third == 0) ? 0 : (third == 1 ? 4 : 9);
    const int pyE = (third == 0) ? 3 : (third == 1 ? 8 : 12);
    const int rS = 2 * pyS, rE = 2 * pyE + 2;

    if (third == 0 && threadIdx.x < 60) {
        int cw4 = threadIdx.x / 15, xp = threadIdx.x % 15;
        pout[((size_t)(b * 8 + ot * 4 + cw4) * 15 + 0) * 15 + xp] = 0xFFFFFFFFu;
    }
    if (third == 2 && threadIdx.x < 60) {
        int cw4 = threadIdx.x / 15, xp = threadIdx.x % 15;
        pout[((size_t)(b * 8 + ot * 4 + cw4) * 15 + 14) * 15 + xp] = 0xFFFFFFFFu;
    }

    int accRun[7];
    #pragma unroll 1
    for (int r = rS; r <= rE; ++r) {
        int s[15];
        #pragma unroll
        for (int x = 0; x < 15; ++x) s[x] = 0;
        #pragma unroll 1
        for (int cw = 0; cw < 3; ++cw) {
            #pragma unroll 1
            for (int kh = 0; kh < 5; ++kh) {
                uint32_t aw[20];
                #pragma unroll
                for (int q = 0; q < 5; ++q)
                    *(uint4*)&aw[4 * q] =
                        *(const uint4*)&al[cw * 992 + (r + kh) * 32 + xs + 4 * q];
                uint32_t wk[5];
                #pragma unroll
                for (int kw = 0; kw < 5; ++kw)
                    wk[kw] = wl[(cw * 25 + kh * 5 + kw) * 129 + ol];
                #pragma unroll
                for (int kw = 0; kw < 5; ++kw)
                    #pragma unroll
                    for (int x = 0; x < 15; ++x)
                        s[x] += __popc(aw[x + kw] ^ wk[kw]);
            }
        }
        int cm[7];
        #pragma unroll
        for (int p = 0; p < 7; ++p)
            cm[p] = min(min(s[2 * p], s[2 * p + 1]), s[2 * p + 2]);

        if (r == rS) {
            #pragma unroll
            for (int p = 0; p < 7; ++p) accRun[p] = cm[p];
        } else if (r & 1) {
            #pragma unroll
            for (int p = 0; p < 7; ++p) accRun[p] = min(accRun[p], cm[p]);
        } else {
            const int yp = r >> 1;
            #pragma unroll
            for (int p = 0; p < 7; ++p) {
                int mn = min(accRun[p], cm[p]);
                float dot = (float)(2400 - 2 * mn);
                bool bit = (dot - bmean) * scale + bbeta < 0.f;
                unsigned long long bal = __ballot(bit);
                int xp = xh * 6 + p + 1;
                if (lane == 0)
                    pout[((size_t)(b * 8 + cwbase) * 15 + yp) * 15 + xp] = (uint32_t)bal;
                if (lane == 32)
                    pout[((size_t)(b * 8 + cwbase + 1) * 15 + yp) * 15 + xp] = (uint32_t)(bal >> 32);
                accRun[p] = cm[p];
            }
            if (threadIdx.x < 8) {
                int cw4 = threadIdx.x & 3, side = threadIdx.x >> 2;
                pout[((size_t)(b * 8 + ot * 4 + cw4) * 15 + yp) * 15 + (side ? 14 : 0)] = 0xFFFFFFFFu;
            }
        }
    }
}

// ---------------------------------------------------------------------------
// 3x3 binconv + bn + sign + pack pad1 (conv3, conv4) v4: O-split 64.
// block 256 = (o 64, yslot 4), grid (4 ygroups, O/64 ot, 128 b).
// ---------------------------------------------------------------------------
template <int CW>
__global__ __launch_bounds__(256) void binconv33_pack(
    const uint32_t* __restrict__ pa, const uint32_t* __restrict__ pw,
    uint32_t* __restrict__ pout, const float* __restrict__ bnp, int O)
{
    constexpr int KW = CW * 9;
    const int yg = blockIdx.x, ot = blockIdx.y, b = blockIdx.z;
    const int CWout = O >> 5;
    const int tid = threadIdx.x;
    __shared__ uint32_t wl[KW * 65];
    __shared__ alignas(16) uint32_t al[CW * 96];

    const uint32_t* pwb = pw + (size_t)(ot * 64) * KW;
    for (int idx = tid; idx < 64 * KW; idx += 256) {
        int o = idx / KW, k = idx % KW;
        wl[k * 65 + o] = pwb[idx];
    }
    const uint32_t* pab = pa + (size_t)b * CW * 225;
    for (int idx = tid; idx < CW * 96; idx += 256) {
        int cw = idx / 96, rr = (idx >> 4) % 6, xp = idx & 15;
        int ry = 4 * yg + rr;
        uint32_t v = 0;
        if (xp < 15 && ry < 15) v = pab[(size_t)cw * 225 + ry * 15 + xp];
        al[idx] = v;
    }
    __syncthreads();

    const int ol = tid & 63;
    const int ys = tid >> 6;
    const int y = 4 * yg + ys;
    int acc[13] = {0,0,0,0,0,0,0,0,0,0,0,0,0};

    #pragma unroll 1
    for (int cw = 0; cw < CW; ++cw) {
        #pragma unroll
        for (int kh = 0; kh < 3; ++kh) {
            uint32_t aw[16];
            #pragma unroll
            for (int q = 0; q < 4; ++q)
                *(uint4*)&aw[4 * q] =
                    *(const uint4*)&al[cw * 96 + (ys + kh) * 16 + 4 * q];
            uint32_t w0 = wl[(cw * 9 + kh * 3 + 0) * 65 + ol];
            uint32_t w1 = wl[(cw * 9 + kh * 3 + 1) * 65 + ol];
            uint32_t w2 = wl[(cw * 9 + kh * 3 + 2) * 65 + ol];
            #pragma unroll
            for (int xx = 0; xx < 13; ++xx)
                acc[xx] += __popc(aw[xx] ^ w0) + __popc(aw[xx + 1] ^ w1)
                         + __popc(aw[xx + 2] ^ w2);
        }
    }

    const int o = ot * 64 + ol;
    float scale = bnp[o] / sqrtf(bnp[3 * O + o] + EPS);
    float m = bnp[2 * O + o], be = bnp[O + o];
    const int cwbase = ot * 2;
    const bool rowvalid = (y < 13);
    const int ypad = y + 1;
    #pragma unroll
    for (int xx = 0; xx < 13; ++xx) {
        float dot = (float)(CW * 288 - 2 * acc[xx]);
        bool bit = (dot - m) * scale + be < 0.f;
        unsigned long long bal = __ballot(bit);
        if (rowvalid) {
            if (ol == 0)
                pout[((size_t)(b * CWout + cwbase) * 15 + ypad) * 15 + xx + 1] = (uint32_t)bal;
            if (ol == 32)
                pout[((size_t)(b * CWout + cwbase + 1) * 15 + ypad) * 15 + xx + 1] = (uint32_t)(bal >> 32);
        }
    }
    if (rowvalid && ol == 0) {
        pout[((size_t)(b * CWout + cwbase) * 15 + ypad) * 15 + 0]  = 0xFFFFFFFFu;
        pout[((size_t)(b * CWout + cwbase) * 15 + ypad) * 15 + 14] = 0xFFFFFFFFu;
    }
    if (rowvalid && ol == 32) {
        pout[((size_t)(b * CWout + cwbase + 1) * 15 + ypad) * 15 + 0]  = 0xFFFFFFFFu;
        pout[((size_t)(b * CWout + cwbase + 1) * 15 + ypad) * 15 + 14] = 0xFFFFFFFFu;
    }
    if (yg == 0 && tid < 30) {
        int cw2 = tid / 15, xp = tid % 15;
        pout[((size_t)(b * CWout + cwbase + cw2) * 15 + 0) * 15 + xp] = 0xFFFFFFFFu;
    }
    if (yg == 3 && tid < 30) {
        int cw2 = tid / 15, xp = tid % 15;
        pout[((size_t)(b * CWout + cwbase + cw2) * 15 + 14) * 15 + xp] = 0xFFFFFFFFu;
    }
}

// ---------------------------------------------------------------------------
// binconv5 + maxpool(13->6) + bn5 + sign -> bytes [b][256][36] v3: O-split 64
// + two pooled rows per block. grid (3 pyg, 4 ot, 128 b),
// block 256 = (o 64, xhalf 2, pooled-row 2).
// ---------------------------------------------------------------------------
__global__ __launch_bounds__(256) void binconv5_pool(
    const uint32_t* __restrict__ pa, const uint32_t* __restrict__ pw,
    unsigned char* __restrict__ sout, const float* __restrict__ bnp)
{
    const int pyg = blockIdx.x, ot = blockIdx.y, b = blockIdx.z;
    const int tid = threadIdx.x;
    __shared__ uint32_t wl[108 * 65];
    __shared__ alignas(16) uint32_t al[12 * 112];
    const uint32_t* pwb = pw + (size_t)(ot * 64) * 108;
    for (int idx = tid; idx < 64 * 108; idx += 256) {
        int o = idx / 108, k = idx % 108;
        wl[k * 65 + o] = pwb[idx];
    }
    const uint32_t* pab = pa + (size_t)b * 12 * 225;
    for (int idx = tid; idx < 12 * 112; idx += 256) {
        int cw = idx / 112, rr = (idx >> 4) % 7, xp = idx & 15;
        int row = 4 * pyg + rr;
        uint32_t v = 0;
        if (xp < 15 && row < 15) v = pab[(size_t)cw * 225 + row * 15 + xp];
        al[idx] = v;
    }
    __syncthreads();

    const int ol = tid & 63;
    const int xh = (tid >> 6) & 1;
    const int pyh = tid >> 7;
    const int py = 2 * pyg + pyh;
    const int xs = xh * 6;
    int s[3][7];
    #pragma unroll
    for (int r = 0; r < 3; ++r)
        #pragma unroll
        for (int xx = 0; xx < 7; ++xx) s[r][xx] = 0;

    #pragma unroll 1
    for (int cw = 0; cw < 12; ++cw) {
        uint32_t aw[5][10];
        #pragma unroll
        for (int rr = 0; rr < 5; ++rr)
            #pragma unroll
            for (int q = 0; q < 5; ++q)
                *(uint2*)&aw[rr][2 * q] =
                    *(const uint2*)&al[cw * 112 + (2 * pyh + rr) * 16 + xs + 2 * q];
        #pragma unroll
        for (int kh = 0; kh < 3; ++kh) {
            uint32_t w0 = wl[(cw * 9 + kh * 3 + 0) * 65 + ol];
            uint32_t w1 = wl[(cw * 9 + kh * 3 + 1) * 65 + ol];
            uint32_t w2 = wl[(cw * 9 + kh * 3 + 2) * 65 + ol];
            #pragma unroll
            for (int r = 0; r < 3; ++r)
                #pragma unroll
                for (int xx = 0; xx < 7; ++xx)
                    s[r][xx] += __popc(aw[r + kh][xx] ^ w0)
                              + __popc(aw[r + kh][xx + 1] ^ w1)
                              + __popc(aw[r + kh][xx + 2] ^ w2);
        }
    }
    const int o = ot * 64 + ol;
    float scale = bnp[o] / sqrtf(bnp[768 + o] + EPS);
    float m = bnp[512 + o], be = bnp[256 + o];
    #pragma unroll
    for (int p = 0; p < 3; ++p) {
        int mn = min(min(s[0][2*p], s[0][2*p+1]), s[0][2*p+2]);
        mn = min(mn, min(min(s[1][2*p], s[1][2*p+1]), s[1][2*p+2]));
        mn = min(mn, min(min(s[2][2*p], s[2][2*p+1]), s[2][2*p+2]));
        float dot = (float)(3456 - 2 * mn);
        bool bit = (dot - m) * scale + be < 0.f;
        sout[(size_t)(b * 256 + o) * 36 + py * 6 + xh * 3 + p] = bit ? 1 : 0;
    }
}

// S5 bytes [128][9216] -> packed words [128][288]
__global__ __launch_bounds__(256) void pack_s5(
    const unsigned char* __restrict__ s, uint32_t* __restrict__ out)
{
    int idx = blockIdx.x * 256 + threadIdx.x;
    if (idx >= 128 * 288) return;
    const uint32_t* p = (const uint32_t*)(s + (size_t)idx * 32);
    uint32_t word = 0;
    #pragma unroll
    for (int q = 0; q < 8; ++q) {
        uint32_t v = p[q];
        word |= ((v & 1u) | ((v >> 7) & 2u) | ((v >> 14) & 4u) | ((v >> 21) & 8u)) << (4 * q);
    }
    out[idx] = word;
}

// ---------------------------------------------------------------------------
// bingemm1: [128,288w] x [4096,288w] -> bn6 -> sign -> packed [128,128w]
// ---------------------------------------------------------------------------
__global__ __launch_bounds__(256) void bingemm1_pack(
    const uint32_t* __restrict__ xp, const uint32_t* __restrict__ wp,
    uint32_t* __restrict__ pout, const float* __restrict__ bnp)
{
    const int ot = blockIdx.x, bt = blockIdx.y;
    __shared__ uint32_t xl[8 * 288];
    for (int i = threadIdx.x; i < 8 * 288; i += 256)
        xl[i] = xp[(size_t)(bt * 8 + i / 288) * 288 + (i % 288)];
    __syncthreads();
    const int o = ot * 256 + threadIdx.x;
    const uint32_t* wr = wp + (size_t)o * 288;
    int acc[8] = {0,0,0,0,0,0,0,0};
    for (int k = 0; k < 288; k += 4) {
        uint4 w4 = *(const uint4*)&wr[k];
        #pragma unroll
        for (int bb = 0; bb < 8; ++bb) {
            uint4 x4 = *(const uint4*)&xl[bb * 288 + k];
            acc[bb] += __popc(w4.x ^ x4.x) + __popc(w4.y ^ x4.y)
                     + __popc(w4.z ^ x4.z) + __popc(w4.w ^ x4.w);
        }
    }
    float scale = bnp[o] / sqrtf(bnp[3 * 4096 + o] + EPS);
    float m = bnp[2 * 4096 + o], be = bnp[4096 + o];
    const int lane = threadIdx.x & 63;
    const int wordbase = ot * 8 + (threadIdx.x >> 6) * 2;
    #pragma unroll
    for (int bb = 0; bb < 8; ++bb) {
        float dot = (float)(9216 - 2 * acc[bb]);
        bool bit = (dot - m) * scale + be < 0.f;
        unsigned long long bal = __ballot(bit);
        if (lane == 0)  pout[(size_t)(bt * 8 + bb) * 128 + wordbase]     = (uint32_t)bal;
        if (lane == 32) pout[(size_t)(bt * 8 + bb) * 128 + wordbase + 1] = (uint32_t)(bal >> 32);
    }
}

// ---------------------------------------------------------------------------
// bingemm2: [128,128w] x [4096,128w] -> bn7 -> relu -> f32 [128,4096]
// ---------------------------------------------------------------------------
__global__ __launch_bounds__(256) void bingemm2_relu(
    const uint32_t* __restrict__ xp, const uint32_t* __restrict__ wp,
    float* __restrict__ outp, const float* __restrict__ bnp)
{
    const int ot = blockIdx.x, bt = blockIdx.y;
    __shared__ uint32_t xl[8 * 128];
    for (int i = threadIdx.x; i < 8 * 128; i += 256)
        xl[i] = xp[(size_t)(bt * 8 + i / 128) * 128 + (i % 128)];
    __syncthreads();
    const int o = ot * 256 + threadIdx.x;
    const uint32_t* wr = wp + (size_t)o * 128;
    int acc[8] = {0,0,0,0,0,0,0,0};
    for (int k = 0; k < 128; k += 4) {
        uint4 w4 = *(const uint4*)&wr[k];
        #pragma unroll
        for (int bb = 0; bb < 8; ++bb) {
            uint4 x4 = *(const uint4*)&xl[bb * 128 + k];
            acc[bb] += __popc(w4.x ^ x4.x) + __popc(w4.y ^ x4.y)
                     + __popc(w4.z ^ x4.z) + __popc(w4.w ^ x4.w);
        }
    }
    float scale = bnp[o] / sqrtf(bnp[3 * 4096 + o] + EPS);
    float m = bnp[2 * 4096 + o], be = bnp[4096 + o];
    #pragma unroll
    for (int bb = 0; bb < 8; ++bb) {
        float dot = (float)(4096 - 2 * acc[bb]);
        float v = (dot - m) * scale + be;
        outp[(size_t)(bt * 8 + bb) * 4096 + o] = fmaxf(v, 0.f);
    }
}

// ---------------------------------------------------------------------------
// fc3: [128,4096] x [1000,4096]^T + bias, K-split 8
// ---------------------------------------------------------------------------
__global__ __launch_bounds__(256) void fc3_partial_kernel(
    const float* __restrict__ in, const float* __restrict__ w, float* __restrict__ part)
{
    const int otile = blockIdx.x * 64;
    const int kbase = blockIdx.y * 512;
    __shared__ float xs[32][132];
    __shared__ float wt[32][68];
    const int tid = threadIdx.x;
    const int ox = (tid & 15) * 4;
    const int bx = (tid >> 4) * 8;
    float acc[4][8];
    #pragma unroll
    for (int i = 0; i < 4; ++i)
        #pragma unroll
        for (int j = 0; j < 8; ++j) acc[i][j] = 0.f;

    for (int kc = 0; kc < 512; kc += 32) {
        __syncthreads();
        #pragma unroll
        for (int j = 0; j < 16; ++j) {
            int idx = tid + j * 256;
            int bb = idx >> 5, kk = idx & 31;
            xs[kk][bb] = in[(size_t)bb * 4096 + kbase + kc + kk];
        }
        #pragma unroll
        for (int j = 0; j < 8; ++j) {
            int idx = tid + j * 256;
            int oo = idx >> 5, kk = idx & 31;
            int og = otile + oo;
            wt[kk][oo] = (og < 1000) ? w[(size_t)og * 4096 + kbase + kc + kk] : 0.f;
        }
        __syncthreads();
        #pragma unroll
        for (int kk = 0; kk < 32; ++kk) {
            float4 wv = *(const float4*)&wt[kk][ox];
            float4 x0 = *(const float4*)&xs[kk][bx];
            float4 x1 = *(const float4*)&xs[kk][bx + 4];
            float wvv[4] = {wv.x, wv.y, wv.z, wv.w};
            float xv[8]  = {x0.x, x0.y, x0.z, x0.w, x1.x, x1.y, x1.z, x1.w};
            #pragma unroll
            for (int i = 0; i < 4; ++i)
                #pragma unroll
                for (int j = 0; j < 8; ++j)
                    acc[i][j] = fmaf(wvv[i], xv[j], acc[i][j]);
        }
    }
    float* pb = part + (size_t)blockIdx.y * 128 * 1024;
    #pragma unroll
    for (int i = 0; i < 4; ++i)
        #pragma unroll
        for (int j = 0; j < 8; ++j)
            pb[(size_t)(bx + j) * 1024 + otile + ox + i] = acc[i][j];
}

__global__ __launch_bounds__(256) void fc3_reduce_kernel(
    const float* __restrict__ part, const float* __restrict__ bias,
    float* __restrict__ out)
{
    int idx = blockIdx.x * 256 + threadIdx.x;
    if (idx >= 128 * 1000) return;
    int o = idx % 1000, b = idx / 1000;
    float s = bias[o];
    #pragma unroll
    for (int k = 0; k < 8; ++k)
        s += part[((size_t)k * 128 + b) * 1024 + o];
    out[idx] = s;
}

// ---------------------------------------------------------------------------
// launch
// ---------------------------------------------------------------------------
extern "C" void kernel_launch(void* const* d_in, const int* in_sizes, int n_in,
                              void* d_out, int out_size, void* d_ws, size_t ws_size,
                              hipStream_t stream)
{
    const float* x        = (const float*)d_in[0];
    const float* conv1_w  = (const float*)d_in[1];
    const float* bconv2_w = (const float*)d_in[2];
    const float* bconv3_w = (const float*)d_in[3];
    const float* bconv4_w = (const float*)d_in[4];
    const float* bconv5_w = (const float*)d_in[5];
    const float* blin1_w  = (const float*)d_in[6];
    const float* blin2_w  = (const float*)d_in[7];
    const float* lin3_w   = (const float*)d_in[8];
    const float* lin3_b   = (const float*)d_in[9];
    const float* bn1 = (const float*)d_in[10];
    const float* bn2 = (const float*)d_in[11];
    const float* bn3 = (const float*)d_in[12];
    const float* bn4 = (const float*)d_in[13];
    const float* bn5 = (const float*)d_in[14];
    const float* bn6 = (const float*)d_in[15];
    const float* bn7 = (const float*)d_in[16];
    float* out = (float*)d_out;

    // workspace layout (bytes, 256-aligned)
    char* ws = (char*)d_ws;
    float*         A    = (float*)(ws + 0);                 // 148,684,800 (channel-last)
    uint32_t*      PB1  = (uint32_t*)(ws + 148684800);      //  1,572,864
    uint32_t*      PB2  = (uint32_t*)(ws + 150257664);      //  1,572,864
    unsigned char* S5   = (unsigned char*)(ws + 152027136); //  1,179,648
    uint32_t*      PFC1 = (uint32_t*)(ws + 153206784);      //    147,456
    uint32_t*      PFC2 = (uint32_t*)(ws + 153354240);      //     65,536
    uint32_t*      PWF1 = (uint32_t*)(ws + 153419776);      //  4,718,592
    uint32_t*      PWF2 = (uint32_t*)(ws + 158138368);      //  2,097,152
    float*         FC2  = (float*)(ws + 160235520);         //  2,097,152
    float*         PART = (float*)(ws + 162332672);         //  4,194,304
    __bf16*        WTH  = (__bf16*)(ws + 166526976);        //    102,400
    __bf16*        WTL  = (__bf16*)(ws + 166629376);        //    102,400
    uint32_t*      PW2  = (uint32_t*)(ws + 166731776);      //     76,800
    uint32_t*      PW3  = (uint32_t*)(ws + 166808576);      //    110,592
    uint32_t*      PW4  = (uint32_t*)(ws + 166919168);      //    165,888
    uint32_t*      PW5  = (uint32_t*)(ws + 167085056);      //    110,592
    // end: 167,195,648

    // 0) all weight prep in one launch (7307 blocks)
    prep_all<<<7307, 256, 0, stream>>>(conv1_w, WTH, WTL,
                                       bconv2_w, PW2, bconv3_w, PW3,
                                       bconv4_w, PW4, bconv5_w, PW5,
                                       blin1_w, PWF1, blin2_w, PWF2);

    // 1) conv1 -> A [128][55][55][96] channel-last
    conv1_mfma<<<dim3(14, 128), 512, 0, stream>>>(x, WTH, WTL, A);

    // 2) stage1: pool+bn1+sign+pack(pad2) -> PB1 [128,3,31,31]
    poolpack1<<<(128 * 3 * 31 * 31 + 255) / 256, 256, 0, stream>>>(A, PB1, bn1);

    // 3) conv2 (fused pool+bn2+pack, streaming) -> PB2 [128,8,15,15]
    binconv2_pool<<<dim3(3, 2, 128), 256, 0, stream>>>(PB1, PW2, PB2, bn2);

    // 4) conv3 (+bn3+pack) -> PB1 [128,12,15,15]
    binconv33_pack<8><<<dim3(4, 6, 128), 256, 0, stream>>>(PB2, PW3, PB1, bn3, 384);

    // 5) conv4 (+bn4+pack) -> PB2 [128,12,15,15]
    binconv33_pack<12><<<dim3(4, 6, 128), 256, 0, stream>>>(PB1, PW4, PB2, bn4, 384);

    // 6) conv5 (fused pool+bn5+sign) -> S5 bytes, then pack -> PFC1 [128,288]
    binconv5_pool<<<dim3(3, 4, 128), 256, 0, stream>>>(PB2, PW5, S5, bn5);
    pack_s5<<<(128 * 288 + 255) / 256, 256, 0, stream>>>(S5, PFC1);

    // 7) bingemm1 + bn6 + sign -> PFC2 [128,128]
    bingemm1_pack<<<dim3(16, 16), 256, 0, stream>>>(PFC1, PWF1, PFC2, bn6);

    // 8) bingemm2 + bn7 + relu -> FC2 [128,4096]
    bingemm2_relu<<<dim3(16, 16), 256, 0, stream>>>(PFC2, PWF2, FC2, bn7);

    // 9) fc3
    fc3_partial_kernel<<<dim3(16, 8), 256, 0, stream>>>(FC2, lin3_w, PART);
    fc3_reduce_kernel<<<(128 * 1000 + 255) / 256, 256, 0, stream>>>(PART, lin3_b, out);
}

// Round 15
// 729.634 us; speedup vs baseline: 1.1410x; 1.1410x over previous
//
#include <hip/hip_runtime.h>
#include <stdint.h>
#include <math.h>
#include <limits.h>

#define EPS 1e-5f

typedef __attribute__((ext_vector_type(4))) __bf16 bf16x4;
typedef __attribute__((ext_vector_type(8))) __bf16 bf16x8;
typedef __attribute__((ext_vector_type(16))) float f32x16;
typedef float f32x4u __attribute__((ext_vector_type(4), aligned(4)));

// ---------------------------------------------------------------------------
// prep_all v2: merged one-shot prep. FC weight packing one-thread-per-word.
// blocks: [0,198) wprep | [198,273) pw2 | [273,381) pw3 | [381,543) pw4 |
//         [543,651) pw5 | [651,5259) pwf1 | [5259,7307) pwf2
// ---------------------------------------------------------------------------
__device__ __forceinline__ void packw_body(
    const float* __restrict__ w, uint32_t* __restrict__ out,
    int C, int KK, int total, int idx)
{
    if (idx >= total) return;
    int kk = idx % KK, t = idx / KK;
    int cw = t % (C / 32); int o = t / (C / 32);
    const float* base = w + ((size_t)o * C + cw * 32) * KK + kk;
    uint32_t word = 0;
    #pragma unroll
    for (int j = 0; j < 32; ++j)
        word |= (base[(size_t)j * KK] < 0.f) ? (1u << j) : 0u;
    out[idx] = word;
}

__device__ __forceinline__ void packword_body(
    const float* __restrict__ in, uint32_t* __restrict__ out, int idx)
{
    const float* base = in + (size_t)idx * 32;   // 128B-aligned
    uint32_t word = 0;
    #pragma unroll
    for (int q = 0; q < 8; ++q) {
        float4 v = *(const float4*)(base + q * 4);
        word |= (v.x < 0.f) ? (1u << (q * 4 + 0)) : 0u;
        word |= (v.y < 0.f) ? (1u << (q * 4 + 1)) : 0u;
        word |= (v.z < 0.f) ? (1u << (q * 4 + 2)) : 0u;
        word |= (v.w < 0.f) ? (1u << (q * 4 + 3)) : 0u;
    }
    out[idx] = word;
}

__global__ __launch_bounds__(256) void prep_all(
    const float* __restrict__ conv1_w, __bf16* __restrict__ wth, __bf16* __restrict__ wtl,
    const float* __restrict__ w2, uint32_t* __restrict__ pw2,
    const float* __restrict__ w3, uint32_t* __restrict__ pw3,
    const float* __restrict__ w4, uint32_t* __restrict__ pw4,
    const float* __restrict__ w5, uint32_t* __restrict__ pw5,
    const float* __restrict__ blin1, uint32_t* __restrict__ pwf1,
    const float* __restrict__ blin2, uint32_t* __restrict__ pwf2)
{
    const int blk = blockIdx.x;
    const int tid = threadIdx.x;
    if (blk < 198) {
        int idx = blk * 256 + tid;   // 96*33*16 = 50688 exact
        if (idx >= 96 * 33 * 16) return;
        int kw = idx & 15;
        int kr = (idx >> 4) % 33;
        int og = idx / (16 * 33);
        int ot = og >> 5, o = og & 31;
        float v = 0.f;
        if (kw < 11) v = conv1_w[og * 363 + kr * 11 + kw];
        __bf16 h = (__bf16)v;
        size_t dst = ((size_t)(ot * 33 + kr) * 32 + o) * 16 + kw;
        wth[dst] = h;
        wtl[dst] = (__bf16)(v - (float)h);
    } else if (blk < 273) {
        packw_body(w2, pw2, 96, 25, 256 * 3 * 25, (blk - 198) * 256 + tid);
    } else if (blk < 381) {
        packw_body(w3, pw3, 256, 9, 384 * 8 * 9, (blk - 273) * 256 + tid);
    } else if (blk < 543) {
        packw_body(w4, pw4, 384, 9, 384 * 12 * 9, (blk - 381) * 256 + tid);
    } else if (blk < 651) {
        packw_body(w5, pw5, 384, 9, 256 * 12 * 9, (blk - 543) * 256 + tid);
    } else if (blk < 5259) {
        packword_body(blin1, pwf1, (blk - 651) * 256 + tid);   // 1,179,648 exact
    } else {
        packword_body(blin2, pwf2, (blk - 5259) * 256 + tid);  //   524,288 exact
    }
}

// ---------------------------------------------------------------------------
// conv1 via MFMA v3 — FINAL (measured best of v3/v4/v5/v6: 177/246/213/220us;
// conv1 is closed, do not restructure further). block = (oy-quad, b),
// 8 waves = (yh, xt). Pixels=A, weights=B -> channel-last out [b][55][55][96].
// ---------------------------------------------------------------------------
__global__ __launch_bounds__(512) void conv1_mfma(
    const float* __restrict__ x, const __bf16* __restrict__ wth,
    const __bf16* __restrict__ wtl, float* __restrict__ out)
{
    const int byq = blockIdx.x;   // 0..13 -> oy = 4*byq + yh
    const int b   = blockIdx.y;
    __shared__ __bf16 ldsbuf[2 * 69 * 264 + 16];
    __bf16* ldsH = ldsbuf;
    __bf16* ldsL = ldsbuf + 69 * 264 + 8;

    const float* xb = x + (size_t)b * 3 * 224 * 224;
    const int iy0 = 16 * byq - 2;
    for (int idx = threadIdx.x; idx < 69 * 33; idx += 512) {
        int r = idx / 33, q = idx % 33;
        int c = r / 23, ir = r % 23;
        int iy = iy0 + ir;
        const float* src = xb + ((size_t)c * 224 + iy) * 224;
        int ix0 = q * 8 - 2;
        bf16x8 hv, lv;
        if ((unsigned)iy < 224u && ix0 >= 0 && ix0 + 7 <= 223) {
            f32x4u f0 = *(const f32x4u*)(src + ix0);
            f32x4u f1 = *(const f32x4u*)(src + ix0 + 4);
            #pragma unroll
            for (int j = 0; j < 4; ++j) {
                __bf16 h0 = (__bf16)f0[j];
                hv[j] = h0; lv[j] = (__bf16)(f0[j] - (float)h0);
                __bf16 h1 = (__bf16)f1[j];
                hv[4 + j] = h1; lv[4 + j] = (__bf16)(f1[j] - (float)h1);
            }
        } else {
            #pragma unroll
            for (int j = 0; j < 8; ++j) {
                int ix = ix0 + j;
                float v = 0.f;
                if ((unsigned)iy < 224u && (unsigned)ix < 224u) v = src[ix];
                __bf16 h = (__bf16)v;
                hv[j] = h;
                lv[j] = (__bf16)(v - (float)h);
            }
        }
        *(bf16x8*)(ldsH + r * 264 + q * 8) = hv;
        *(bf16x8*)(ldsL + r * 264 + q * 8) = lv;
    }
    __syncthreads();

    const int wv = threadIdx.x >> 6;
    const int l  = threadIdx.x & 63;
    const int yh = wv >> 1, xt = wv & 1;
    const int col = l & 31, kg = l >> 5;
    const int oy = 4 * byq + yh;

    f32x16 acc0 = {}, acc1 = {}, acc2 = {};
    const int bpos = 4 * (xt * 32 + col) + 8 * kg;
    const int wofs = col * 16 + kg * 8;

    for (int c = 0; c < 3; ++c) {
        #pragma unroll
        for (int kh = 0; kh < 11; ++kh) {
            const int kr = c * 11 + kh;
            const int rowoff = (c * 23 + 4 * yh + kh) * 264 + bpos;
            bf16x4 bh0 = *(const bf16x4*)(ldsH + rowoff);
            bf16x4 bh1 = *(const bf16x4*)(ldsH + rowoff + 4);
            bf16x4 bl0 = *(const bf16x4*)(ldsL + rowoff);
            bf16x4 bl1 = *(const bf16x4*)(ldsL + rowoff + 4);
            bf16x8 bh = __builtin_shufflevector(bh0, bh1, 0, 1, 2, 3, 4, 5, 6, 7);
            bf16x8 bl = __builtin_shufflevector(bl0, bl1, 0, 1, 2, 3, 4, 5, 6, 7);
            {
                bf16x8 ah = *(const bf16x8*)(wth + (size_t)kr * 512 + wofs);
                bf16x8 aL = *(const bf16x8*)(wtl + (size_t)kr * 512 + wofs);
                acc0 = __builtin_amdgcn_mfma_f32_32x32x16_bf16(bh, ah, acc0, 0, 0, 0);
                acc0 = __builtin_amdgcn_mfma_f32_32x32x16_bf16(bl, ah, acc0, 0, 0, 0);
                acc0 = __builtin_amdgcn_mfma_f32_32x32x16_bf16(bh, aL, acc0, 0, 0, 0);
            }
            {
                bf16x8 ah = *(const bf16x8*)(wth + (size_t)(33 + kr) * 512 + wofs);
                bf16x8 aL = *(const bf16x8*)(wtl + (size_t)(33 + kr) * 512 + wofs);
                acc1 = __builtin_amdgcn_mfma_f32_32x32x16_bf16(bh, ah, acc1, 0, 0, 0);
                acc1 = __builtin_amdgcn_mfma_f32_32x32x16_bf16(bl, ah, acc1, 0, 0, 0);
                acc1 = __builtin_amdgcn_mfma_f32_32x32x16_bf16(bh, aL, acc1, 0, 0, 0);
            }
            {
                bf16x8 ah = *(const bf16x8*)(wth + (size_t)(66 + kr) * 512 + wofs);
                bf16x8 aL = *(const bf16x8*)(wtl + (size_t)(66 + kr) * 512 + wofs);
                acc2 = __builtin_amdgcn_mfma_f32_32x32x16_bf16(bh, ah, acc2, 0, 0, 0);
                acc2 = __builtin_amdgcn_mfma_f32_32x32x16_bf16(bl, ah, acc2, 0, 0, 0);
                acc2 = __builtin_amdgcn_mfma_f32_32x32x16_bf16(bh, aL, acc2, 0, 0, 0);
            }
        }
    }

    if (oy < 55) {
        #pragma unroll
        for (int i = 0; i < 16; ++i) {
            int oxr = (i & 3) + 8 * (i >> 2) + 4 * kg;
            int ox = xt * 32 + oxr;
            if (ox < 55) {
                float* p = out + ((size_t)(b * 55 + oy) * 55 + ox) * 96 + col;
                p[0]  = acc0[i];
                p[32] = acc1[i];
                p[64] = acc2[i];
            }
        }
    }
}

// ---------------------------------------------------------------------------
// stage1 v2: A [b][55][55][96] (channel-last) -> maxpool3x3s2 -> bn1 -> sign
// -> pack pad2 -> PB1 [128,3,31,31]. Vectorized float4 channel reads.
// ---------------------------------------------------------------------------
__global__ __launch_bounds__(256) void poolpack1(
    const float* __restrict__ A, uint32_t* __restrict__ pout,
    const float* __restrict__ bnp)
{
    int idx = blockIdx.x * 256 + threadIdx.x;
    if (idx >= 128 * 3 * 31 * 31) return;
    int xp = idx % 31, t = idx / 31;
    int yp = t % 31; t /= 31;
    int cw = t % 3; int b = t / 3;
    uint32_t word = 0xFFFFFFFFu;
    if (yp >= 2 && yp <= 28 && xp >= 2 && xp <= 28) {
        int py = yp - 2, px = xp - 2;
        const float* base = A + ((size_t)(b * 55 + 2 * py) * 55 + 2 * px) * 96 + cw * 32;
        word = 0u;
        #pragma unroll
        for (int q = 0; q < 8; ++q) {
            float4 mx = *(const float4*)(base + q * 4);
            #pragma unroll
            for (int dy = 0; dy < 3; ++dy)
                #pragma unroll
                for (int dx = 0; dx < 3; ++dx) {
                    if (dy == 0 && dx == 0) continue;
                    float4 v = *(const float4*)(base + (dy * 55 + dx) * 96 + q * 4);
                    mx.x = fmaxf(mx.x, v.x); mx.y = fmaxf(mx.y, v.y);
                    mx.z = fmaxf(mx.z, v.z); mx.w = fmaxf(mx.w, v.w);
                }
            float mm[4] = {mx.x, mx.y, mx.z, mx.w};
            #pragma unroll
            for (int j = 0; j < 4; ++j) {
                int c = cw * 32 + q * 4 + j;
                float scale = bnp[c] / sqrtf(bnp[288 + c] + EPS);
                float bnv = (mm[j] - bnp[192 + c]) * scale + bnp[96 + c];
                if (bnv < 0.f) word |= 1u << (q * 4 + j);
            }
        }
    }
    pout[idx] = word;
}

// ---------------------------------------------------------------------------
// binconv2 + maxpool + bn2 + sign + pack pad1, v3 STREAMING.
// grid (3, 2, 128), block 256 = (o_local 128, xhalf 2)
// ---------------------------------------------------------------------------
__global__ __launch_bounds__(256) void binconv2_pool(
    const uint32_t* __restrict__ pa, const uint32_t* __restrict__ pw,
    uint32_t* __restrict__ pout, const float* __restrict__ bnp)
{
    const int third = blockIdx.x, ot = blockIdx.y, b = blockIdx.z;
    __shared__ uint32_t wl[75 * 129];
    __shared__ alignas(16) uint32_t al[2976];

    const uint32_t* pwb = pw + (size_t)(ot * 128) * 75;
    for (int idx = threadIdx.x; idx < 128 * 75; idx += 256) {
        int o = idx / 75, k = idx % 75;
        wl[k * 129 + o] = pwb[idx];
    }
    const uint32_t* pab = pa + (size_t)b * 3 * 961;
    for (int idx = threadIdx.x; idx < 2976; idx += 256) {
        int cw = idx / 992, rem = idx - cw * 992;
        int row = rem >> 5, xp = rem & 31;
        al[idx] = (xp < 31) ? pab[(size_t)cw * 961 + row * 31 + xp] : 0u;
    }
    __syncthreads();

    const int ol = threadIdx.x & 127;
    const int xh = threadIdx.x >> 7;
    const int xs = xh * 12;
    const int o = ot * 128 + ol;
    const float scale = bnp[o] / sqrtf(bnp[768 + o] + EPS);
    const float bmean = bnp[512 + o], bbeta = bnp[256 + o];
    const int lane = threadIdx.x & 63;
    const int cwbase = ot * 4 + ((threadIdx.x >> 6) & 1) * 2;

    const int pyS = (third == 0) ? 0 : (third == 1 ? 4 : 9);
    const int pyE = (third == 0) ? 3 : (third == 1 ? 8 : 12);
    const int rS = 2 * pyS, rE = 2 * pyE + 2;

    if (third == 0 && threadIdx.x < 60) {
        int cw4 = threadIdx.x / 15, xp = threadIdx.x % 15;
        pout[((size_t)(b * 8 + ot * 4 + cw4) * 15 + 0) * 15 + xp] = 0xFFFFFFFFu;
    }
    if (third == 2 && threadIdx.x < 60) {
        int cw4 = threadIdx.x / 15, xp = threadIdx.x % 15;
        pout[((size_t)(b * 8 + ot * 4 + cw4) * 15 + 14) * 15 + xp] = 0xFFFFFFFFu;
    }

    int accRun[7];
    #pragma unroll 1
    for (int r = rS; r <= rE; ++r) {
        int s[15];
        #pragma unroll
        for (int x = 0; x < 15; ++x) s[x] = 0;
        #pragma unroll 1
        for (int cw = 0; cw < 3; ++cw) {
            #pragma unroll 1
            for (int kh = 0; kh < 5; ++kh) {
                uint32_t aw[20];
                #pragma unroll
                for (int q = 0; q < 5; ++q)
                    *(uint4*)&aw[4 * q] =
                        *(const uint4*)&al[cw * 992 + (r + kh) * 32 + xs + 4 * q];
                uint32_t wk[5];
                #pragma unroll
                for (int kw = 0; kw < 5; ++kw)
                    wk[kw] = wl[(cw * 25 + kh * 5 + kw) * 129 + ol];
                #pragma unroll
                for (int kw = 0; kw < 5; ++kw)
                    #pragma unroll
                    for (int x = 0; x < 15; ++x)
                        s[x] += __popc(aw[x + kw] ^ wk[kw]);
            }
        }
        int cm[7];
        #pragma unroll
        for (int p = 0; p < 7; ++p)
            cm[p] = min(min(s[2 * p], s[2 * p + 1]), s[2 * p + 2]);

        if (r == rS) {
            #pragma unroll
            for (int p = 0; p < 7; ++p) accRun[p] = cm[p];
        } else if (r & 1) {
            #pragma unroll
            for (int p = 0; p < 7; ++p) accRun[p] = min(accRun[p], cm[p]);
        } else {
            const int yp = r >> 1;
            #pragma unroll
            for (int p = 0; p < 7; ++p) {
                int mn = min(accRun[p], cm[p]);
                float dot = (float)(2400 - 2 * mn);
                bool bit = (dot - bmean) * scale + bbeta < 0.f;
                unsigned long long bal = __ballot(bit);
                int xp = xh * 6 + p + 1;
                if (lane == 0)
                    pout[((size_t)(b * 8 + cwbase) * 15 + yp) * 15 + xp] = (uint32_t)bal;
                if (lane == 32)
                    pout[((size_t)(b * 8 + cwbase + 1) * 15 + yp) * 15 + xp] = (uint32_t)(bal >> 32);
                accRun[p] = cm[p];
            }
            if (threadIdx.x < 8) {
                int cw4 = threadIdx.x & 3, side = threadIdx.x >> 2;
                pout[((size_t)(b * 8 + ot * 4 + cw4) * 15 + yp) * 15 + (side ? 14 : 0)] = 0xFFFFFFFFu;
            }
        }
    }
}

// ---------------------------------------------------------------------------
// 3x3 binconv + bn + sign + pack pad1 (conv3, conv4) v4: O-split 64.
// block 256 = (o 64, yslot 4), grid (4 ygroups, O/64 ot, 128 b).
// ---------------------------------------------------------------------------
template <int CW>
__global__ __launch_bounds__(256) void binconv33_pack(
    const uint32_t* __restrict__ pa, const uint32_t* __restrict__ pw,
    uint32_t* __restrict__ pout, const float* __restrict__ bnp, int O)
{
    constexpr int KW = CW * 9;
    const int yg = blockIdx.x, ot = blockIdx.y, b = blockIdx.z;
    const int CWout = O >> 5;
    const int tid = threadIdx.x;
    __shared__ uint32_t wl[KW * 65];
    __shared__ alignas(16) uint32_t al[CW * 96];

    const uint32_t* pwb = pw + (size_t)(ot * 64) * KW;
    for (int idx = tid; idx < 64 * KW; idx += 256) {
        int o = idx / KW, k = idx % KW;
        wl[k * 65 + o] = pwb[idx];
    }
    const uint32_t* pab = pa + (size_t)b * CW * 225;
    for (int idx = tid; idx < CW * 96; idx += 256) {
        int cw = idx / 96, rr = (idx >> 4) % 6, xp = idx & 15;
        int ry = 4 * yg + rr;
        uint32_t v = 0;
        if (xp < 15 && ry < 15) v = pab[(size_t)cw * 225 + ry * 15 + xp];
        al[idx] = v;
    }
    __syncthreads();

    const int ol = tid & 63;
    const int ys = tid >> 6;
    const int y = 4 * yg + ys;
    int acc[13] = {0,0,0,0,0,0,0,0,0,0,0,0,0};

    #pragma unroll 1
    for (int cw = 0; cw < CW; ++cw) {
        #pragma unroll
        for (int kh = 0; kh < 3; ++kh) {
            uint32_t aw[16];
            #pragma unroll
            for (int q = 0; q < 4; ++q)
                *(uint4*)&aw[4 * q] =
                    *(const uint4*)&al[cw * 96 + (ys + kh) * 16 + 4 * q];
            uint32_t w0 = wl[(cw * 9 + kh * 3 + 0) * 65 + ol];
            uint32_t w1 = wl[(cw * 9 + kh * 3 + 1) * 65 + ol];
            uint32_t w2 = wl[(cw * 9 + kh * 3 + 2) * 65 + ol];
            #pragma unroll
            for (int xx = 0; xx < 13; ++xx)
                acc[xx] += __popc(aw[xx] ^ w0) + __popc(aw[xx + 1] ^ w1)
                         + __popc(aw[xx + 2] ^ w2);
        }
    }

    const int o = ot * 64 + ol;
    float scale = bnp[o] / sqrtf(bnp[3 * O + o] + EPS);
    float m = bnp[2 * O + o], be = bnp[O + o];
    const int cwbase = ot * 2;
    const bool rowvalid = (y < 13);
    const int ypad = y + 1;
    #pragma unroll
    for (int xx = 0; xx < 13; ++xx) {
        float dot = (float)(CW * 288 - 2 * acc[xx]);
        bool bit = (dot - m) * scale + be < 0.f;
        unsigned long long bal = __ballot(bit);
        if (rowvalid) {
            if (ol == 0)
                pout[((size_t)(b * CWout + cwbase) * 15 + ypad) * 15 + xx + 1] = (uint32_t)bal;
            if (ol == 32)
                pout[((size_t)(b * CWout + cwbase + 1) * 15 + ypad) * 15 + xx + 1] = (uint32_t)(bal >> 32);
        }
    }
    if (rowvalid && ol == 0) {
        pout[((size_t)(b * CWout + cwbase) * 15 + ypad) * 15 + 0]  = 0xFFFFFFFFu;
        pout[((size_t)(b * CWout + cwbase) * 15 + ypad) * 15 + 14] = 0xFFFFFFFFu;
    }
    if (rowvalid && ol == 32) {
        pout[((size_t)(b * CWout + cwbase + 1) * 15 + ypad) * 15 + 0]  = 0xFFFFFFFFu;
        pout[((size_t)(b * CWout + cwbase + 1) * 15 + ypad) * 15 + 14] = 0xFFFFFFFFu;
    }
    if (yg == 0 && tid < 30) {
        int cw2 = tid / 15, xp = tid % 15;
        pout[((size_t)(b * CWout + cwbase + cw2) * 15 + 0) * 15 + xp] = 0xFFFFFFFFu;
    }
    if (yg == 3 && tid < 30) {
        int cw2 = tid / 15, xp = tid % 15;
        pout[((size_t)(b * CWout + cwbase + cw2) * 15 + 14) * 15 + xp] = 0xFFFFFFFFu;
    }
}

// ---------------------------------------------------------------------------
// binconv5 + maxpool(13->6) + bn5 + sign -> bytes [b][256][36] v3: O-split 64
// + two pooled rows per block. grid (3 pyg, 4 ot, 128 b),
// block 256 = (o 64, xhalf 2, pooled-row 2).
// ---------------------------------------------------------------------------
__global__ __launch_bounds__(256) void binconv5_pool(
    const uint32_t* __restrict__ pa, const uint32_t* __restrict__ pw,
    unsigned char* __restrict__ sout, const float* __restrict__ bnp)
{
    const int pyg = blockIdx.x, ot = blockIdx.y, b = blockIdx.z;
    const int tid = threadIdx.x;
    __shared__ uint32_t wl[108 * 65];
    __shared__ alignas(16) uint32_t al[12 * 112];
    const uint32_t* pwb = pw + (size_t)(ot * 64) * 108;
    for (int idx = tid; idx < 64 * 108; idx += 256) {
        int o = idx / 108, k = idx % 108;
        wl[k * 65 + o] = pwb[idx];
    }
    const uint32_t* pab = pa + (size_t)b * 12 * 225;
    for (int idx = tid; idx < 12 * 112; idx += 256) {
        int cw = idx / 112, rr = (idx >> 4) % 7, xp = idx & 15;
        int row = 4 * pyg + rr;
        uint32_t v = 0;
        if (xp < 15 && row < 15) v = pab[(size_t)cw * 225 + row * 15 + xp];
        al[idx] = v;
    }
    __syncthreads();

    const int ol = tid & 63;
    const int xh = (tid >> 6) & 1;
    const int pyh = tid >> 7;
    const int py = 2 * pyg + pyh;
    const int xs = xh * 6;
    int s[3][7];
    #pragma unroll
    for (int r = 0; r < 3; ++r)
        #pragma unroll
        for (int xx = 0; xx < 7; ++xx) s[r][xx] = 0;

    #pragma unroll 1
    for (int cw = 0; cw < 12; ++cw) {
        uint32_t aw[5][10];
        #pragma unroll
        for (int rr = 0; rr < 5; ++rr)
            #pragma unroll
            for (int q = 0; q < 5; ++q)
                *(uint2*)&aw[rr][2 * q] =
                    *(const uint2*)&al[cw * 112 + (2 * pyh + rr) * 16 + xs + 2 * q];
        #pragma unroll
        for (int kh = 0; kh < 3; ++kh) {
            uint32_t w0 = wl[(cw * 9 + kh * 3 + 0) * 65 + ol];
            uint32_t w1 = wl[(cw * 9 + kh * 3 + 1) * 65 + ol];
            uint32_t w2 = wl[(cw * 9 + kh * 3 + 2) * 65 + ol];
            #pragma unroll
            for (int r = 0; r < 3; ++r)
                #pragma unroll
                for (int xx = 0; xx < 7; ++xx)
                    s[r][xx] += __popc(aw[r + kh][xx] ^ w0)
                              + __popc(aw[r + kh][xx + 1] ^ w1)
                              + __popc(aw[r + kh][xx + 2] ^ w2);
        }
    }
    const int o = ot * 64 + ol;
    float scale = bnp[o] / sqrtf(bnp[768 + o] + EPS);
    float m = bnp[512 + o], be = bnp[256 + o];
    #pragma unroll
    for (int p = 0; p < 3; ++p) {
        int mn = min(min(s[0][2*p], s[0][2*p+1]), s[0][2*p+2]);
        mn = min(mn, min(min(s[1][2*p], s[1][2*p+1]), s[1][2*p+2]));
        mn = min(mn, min(min(s[2][2*p], s[2][2*p+1]), s[2][2*p+2]));
        float dot = (float)(3456 - 2 * mn);
        bool bit = (dot - m) * scale + be < 0.f;
        sout[(size_t)(b * 256 + o) * 36 + py * 6 + xh * 3 + p] = bit ? 1 : 0;
    }
}

// S5 bytes [128][9216] -> packed words [128][288]
__global__ __launch_bounds__(256) void pack_s5(
    const unsigned char* __restrict__ s, uint32_t* __restrict__ out)
{
    int idx = blockIdx.x * 256 + threadIdx.x;
    if (idx >= 128 * 288) return;
    const uint32_t* p = (const uint32_t*)(s + (size_t)idx * 32);
    uint32_t word = 0;
    #pragma unroll
    for (int q = 0; q < 8; ++q) {
        uint32_t v = p[q];
        word |= ((v & 1u) | ((v >> 7) & 2u) | ((v >> 14) & 4u) | ((v >> 21) & 8u)) << (4 * q);
    }
    out[idx] = word;
}

// ---------------------------------------------------------------------------
// bingemm1: [128,288w] x [4096,288w] -> bn6 -> sign -> packed [128,128w]
// ---------------------------------------------------------------------------
__global__ __launch_bounds__(256) void bingemm1_pack(
    const uint32_t* __restrict__ xp, const uint32_t* __restrict__ wp,
    uint32_t* __restrict__ pout, const float* __restrict__ bnp)
{
    const int ot = blockIdx.x, bt = blockIdx.y;
    __shared__ uint32_t xl[8 * 288];
    for (int i = threadIdx.x; i < 8 * 288; i += 256)
        xl[i] = xp[(size_t)(bt * 8 + i / 288) * 288 + (i % 288)];
    __syncthreads();
    const int o = ot * 256 + threadIdx.x;
    const uint32_t* wr = wp + (size_t)o * 288;
    int acc[8] = {0,0,0,0,0,0,0,0};
    for (int k = 0; k < 288; k += 4) {
        uint4 w4 = *(const uint4*)&wr[k];
        #pragma unroll
        for (int bb = 0; bb < 8; ++bb) {
            uint4 x4 = *(const uint4*)&xl[bb * 288 + k];
            acc[bb] += __popc(w4.x ^ x4.x) + __popc(w4.y ^ x4.y)
                     + __popc(w4.z ^ x4.z) + __popc(w4.w ^ x4.w);
        }
    }
    float scale = bnp[o] / sqrtf(bnp[3 * 4096 + o] + EPS);
    float m = bnp[2 * 4096 + o], be = bnp[4096 + o];
    const int lane = threadIdx.x & 63;
    const int wordbase = ot * 8 + (threadIdx.x >> 6) * 2;
    #pragma unroll
    for (int bb = 0; bb < 8; ++bb) {
        float dot = (float)(9216 - 2 * acc[bb]);
        bool bit = (dot - m) * scale + be < 0.f;
        unsigned long long bal = __ballot(bit);
        if (lane == 0)  pout[(size_t)(bt * 8 + bb) * 128 + wordbase]     = (uint32_t)bal;
        if (lane == 32) pout[(size_t)(bt * 8 + bb) * 128 + wordbase + 1] = (uint32_t)(bal >> 32);
    }
}

// ---------------------------------------------------------------------------
// bingemm2: [128,128w] x [4096,128w] -> bn7 -> relu -> f32 [128,4096]
// ---------------------------------------------------------------------------
__global__ __launch_bounds__(256) void bingemm2_relu(
    const uint32_t* __restrict__ xp, const uint32_t* __restrict__ wp,
    float* __restrict__ outp, const float* __restrict__ bnp)
{
    const int ot = blockIdx.x, bt = blockIdx.y;
    __shared__ uint32_t xl[8 * 128];
    for (int i = threadIdx.x; i < 8 * 128; i += 256)
        xl[i] = xp[(size_t)(bt * 8 + i / 128) * 128 + (i % 128)];
    __syncthreads();
    const int o = ot * 256 + threadIdx.x;
    const uint32_t* wr = wp + (size_t)o * 128;
    int acc[8] = {0,0,0,0,0,0,0,0};
    for (int k = 0; k < 128; k += 4) {
        uint4 w4 = *(const uint4*)&wr[k];
        #pragma unroll
        for (int bb = 0; bb < 8; ++bb) {
            uint4 x4 = *(const uint4*)&xl[bb * 128 + k];
            acc[bb] += __popc(w4.x ^ x4.x) + __popc(w4.y ^ x4.y)
                     + __popc(w4.z ^ x4.z) + __popc(w4.w ^ x4.w);
        }
    }
    float scale = bnp[o] / sqrtf(bnp[3 * 4096 + o] + EPS);
    float m = bnp[2 * 4096 + o], be = bnp[4096 + o];
    #pragma unroll
    for (int bb = 0; bb < 8; ++bb) {
        float dot = (float)(4096 - 2 * acc[bb]);
        float v = (dot - m) * scale + be;
        outp[(size_t)(bt * 8 + bb) * 4096 + o] = fmaxf(v, 0.f);
    }
}

// ---------------------------------------------------------------------------
// fc3: [128,4096] x [1000,4096]^T + bias, K-split 16 (256 blocks -> full GPU)
// ---------------------------------------------------------------------------
__global__ __launch_bounds__(256) void fc3_partial_kernel(
    const float* __restrict__ in, const float* __restrict__ w, float* __restrict__ part)
{
    const int otile = blockIdx.x * 64;
    const int kbase = blockIdx.y * 256;
    __shared__ float xs[32][132];
    __shared__ float wt[32][68];
    const int tid = threadIdx.x;
    const int ox = (tid & 15) * 4;
    const int bx = (tid >> 4) * 8;
    float acc[4][8];
    #pragma unroll
    for (int i = 0; i < 4; ++i)
        #pragma unroll
        for (int j = 0; j < 8; ++j) acc[i][j] = 0.f;

    for (int kc = 0; kc < 256; kc += 32) {
        __syncthreads();
        #pragma unroll
        for (int j = 0; j < 16; ++j) {
            int idx = tid + j * 256;
            int bb = idx >> 5, kk = idx & 31;
            xs[kk][bb] = in[(size_t)bb * 4096 + kbase + kc + kk];
        }
        #pragma unroll
        for (int j = 0; j < 8; ++j) {
            int idx = tid + j * 256;
            int oo = idx >> 5, kk = idx & 31;
            int og = otile + oo;
            wt[kk][oo] = (og < 1000) ? w[(size_t)og * 4096 + kbase + kc + kk] : 0.f;
        }
        __syncthreads();
        #pragma unroll
        for (int kk = 0; kk < 32; ++kk) {
            float4 wv = *(const float4*)&wt[kk][ox];
            float4 x0 = *(const float4*)&xs[kk][bx];
            float4 x1 = *(const float4*)&xs[kk][bx + 4];
            float wvv[4] = {wv.x, wv.y, wv.z, wv.w};
            float xv[8]  = {x0.x, x0.y, x0.z, x0.w, x1.x, x1.y, x1.z, x1.w};
            #pragma unroll
            for (int i = 0; i < 4; ++i)
                #pragma unroll
                for (int j = 0; j < 8; ++j)
                    acc[i][j] = fmaf(wvv[i], xv[j], acc[i][j]);
        }
    }
    float* pb = part + (size_t)blockIdx.y * 128 * 1024;
    #pragma unroll
    for (int i = 0; i < 4; ++i)
        #pragma unroll
        for (int j = 0; j < 8; ++j)
            pb[(size_t)(bx + j) * 1024 + otile + ox + i] = acc[i][j];
}

__global__ __launch_bounds__(256) void fc3_reduce_kernel(
    const float* __restrict__ part, const float* __restrict__ bias,
    float* __restrict__ out)
{
    int idx = blockIdx.x * 256 + threadIdx.x;
    if (idx >= 128 * 1000) return;
    int o = idx % 1000, b = idx / 1000;
    float s = bias[o];
    #pragma unroll
    for (int k = 0; k < 16; ++k)
        s += part[((size_t)k * 128 + b) * 1024 + o];
    out[idx] = s;
}

// ---------------------------------------------------------------------------
// launch
// ---------------------------------------------------------------------------
extern "C" void kernel_launch(void* const* d_in, const int* in_sizes, int n_in,
                              void* d_out, int out_size, void* d_ws, size_t ws_size,
                              hipStream_t stream)
{
    const float* x        = (const float*)d_in[0];
    const float* conv1_w  = (const float*)d_in[1];
    const float* bconv2_w = (const float*)d_in[2];
    const float* bconv3_w = (const float*)d_in[3];
    const float* bconv4_w = (const float*)d_in[4];
    const float* bconv5_w = (const float*)d_in[5];
    const float* blin1_w  = (const float*)d_in[6];
    const float* blin2_w  = (const float*)d_in[7];
    const float* lin3_w   = (const float*)d_in[8];
    const float* lin3_b   = (const float*)d_in[9];
    const float* bn1 = (const float*)d_in[10];
    const float* bn2 = (const float*)d_in[11];
    const float* bn3 = (const float*)d_in[12];
    const float* bn4 = (const float*)d_in[13];
    const float* bn5 = (const float*)d_in[14];
    const float* bn6 = (const float*)d_in[15];
    const float* bn7 = (const float*)d_in[16];
    float* out = (float*)d_out;

    // workspace layout (bytes, 256-aligned)
    char* ws = (char*)d_ws;
    float*         A    = (float*)(ws + 0);                 // 148,684,800 (channel-last)
    uint32_t*      PB1  = (uint32_t*)(ws + 148684800);      //  1,572,864
    uint32_t*      PB2  = (uint32_t*)(ws + 150257664);      //  1,572,864
    unsigned char* S5   = (unsigned char*)(ws + 152027136); //  1,179,648
    uint32_t*      PFC1 = (uint32_t*)(ws + 153206784);      //    147,456
    uint32_t*      PFC2 = (uint32_t*)(ws + 153354240);      //     65,536
    uint32_t*      PWF1 = (uint32_t*)(ws + 153419776);      //  4,718,592
    uint32_t*      PWF2 = (uint32_t*)(ws + 158138368);      //  2,097,152
    float*         FC2  = (float*)(ws + 160235520);         //  2,097,152
    __bf16*        WTH  = (__bf16*)(ws + 162332672);        //    102,400
    __bf16*        WTL  = (__bf16*)(ws + 162435072);        //    102,400
    uint32_t*      PW2  = (uint32_t*)(ws + 162537472);      //     76,800
    uint32_t*      PW3  = (uint32_t*)(ws + 162614272);      //    110,592
    uint32_t*      PW4  = (uint32_t*)(ws + 162724864);      //    165,888
    uint32_t*      PW5  = (uint32_t*)(ws + 162890752);      //    110,592
    float*         PART = (float*)(ws + 163001600);         //  8,388,608 (K-split 16)
    // end: 171,390,208 (round-1 build used 197MB of ws, so this fits)

    // 0) all weight prep in one launch (7307 blocks)
    prep_all<<<7307, 256, 0, stream>>>(conv1_w, WTH, WTL,
                                       bconv2_w, PW2, bconv3_w, PW3,
                                       bconv4_w, PW4, bconv5_w, PW5,
                                       blin1_w, PWF1, blin2_w, PWF2);

    // 1) conv1 -> A [128][55][55][96] channel-last
    conv1_mfma<<<dim3(14, 128), 512, 0, stream>>>(x, WTH, WTL, A);

    // 2) stage1: pool+bn1+sign+pack(pad2) -> PB1 [128,3,31,31]
    poolpack1<<<(128 * 3 * 31 * 31 + 255) / 256, 256, 0, stream>>>(A, PB1, bn1);

    // 3) conv2 (fused pool+bn2+pack, streaming) -> PB2 [128,8,15,15]
    binconv2_pool<<<dim3(3, 2, 128), 256, 0, stream>>>(PB1, PW2, PB2, bn2);

    // 4) conv3 (+bn3+pack) -> PB1 [128,12,15,15]
    binconv33_pack<8><<<dim3(4, 6, 128), 256, 0, stream>>>(PB2, PW3, PB1, bn3, 384);

    // 5) conv4 (+bn4+pack) -> PB2 [128,12,15,15]
    binconv33_pack<12><<<dim3(4, 6, 128), 256, 0, stream>>>(PB1, PW4, PB2, bn4, 384);

    // 6) conv5 (fused pool+bn5+sign) -> S5 bytes, then pack -> PFC1 [128,288]
    binconv5_pool<<<dim3(3, 4, 128), 256, 0, stream>>>(PB2, PW5, S5, bn5);
    pack_s5<<<(128 * 288 + 255) / 256, 256, 0, stream>>>(S5, PFC1);

    // 7) bingemm1 + bn6 + sign -> PFC2 [128,128]
    bingemm1_pack<<<dim3(16, 16), 256, 0, stream>>>(PFC1, PWF1, PFC2, bn6);

    // 8) bingemm2 + bn7 + relu -> FC2 [128,4096]
    bingemm2_relu<<<dim3(16, 16), 256, 0, stream>>>(PFC2, PWF2, FC2, bn7);

    // 9) fc3 (K-split 16 -> 256 blocks)
    fc3_partial_kernel<<<dim3(16, 16), 256, 0, stream>>>(FC2, lin3_w, PART);
    fc3_reduce_kernel<<<(128 * 1000 + 255) / 256, 256, 0, stream>>>(PART, lin3_b, out);
}